// Round 1
// baseline (148.215 us; speedup 1.0000x reference)
//
#include <hip/hip_runtime.h>

#define IN_F 8192
#define OUT_F 8192
#define BLOCK 256

__global__ __launch_bounds__(BLOCK) void snn_fused_kernel(
    const float* __restrict__ x,        // [IN_F] spike_input
    const float* __restrict__ syn,      // [OUT_F, IN_F] synapse_states
    const float* __restrict__ mp,       // [OUT_F] membrane_potential
    const float* __restrict__ at,       // [OUT_F] adaptive_threshold
    const float* __restrict__ trace,    // [OUT_F, IN_F] eligibility_trace
    float* __restrict__ spikes_out,     // [OUT_F]
    float* __restrict__ vmem_out,       // [OUT_F]
    float* __restrict__ trace_out,      // [OUT_F, IN_F]
    float* __restrict__ thr_out)        // [OUT_F]
{
    const int o   = blockIdx.x;
    const int tid = threadIdx.x;
    const int n4  = IN_F / 4;  // 2048 float4 per row

    const float4* __restrict__ syn4 = reinterpret_cast<const float4*>(syn + (size_t)o * IN_F);
    const float4* __restrict__ x4   = reinterpret_cast<const float4*>(x);

    // ---- Phase 1: masked row-sum  current[o] = sum_i (syn[o,i] > 50) * x[i]
    float partial = 0.0f;
    #pragma unroll 4
    for (int i = tid; i < n4; i += BLOCK) {
        float4 s  = syn4[i];
        float4 xv = x4[i];
        partial += (s.x > 50.0f ? xv.x : 0.0f);
        partial += (s.y > 50.0f ? xv.y : 0.0f);
        partial += (s.z > 50.0f ? xv.z : 0.0f);
        partial += (s.w > 50.0f ? xv.w : 0.0f);
    }

    // wave (64-lane) butterfly reduce
    #pragma unroll
    for (int off = 32; off > 0; off >>= 1)
        partial += __shfl_down(partial, off, 64);

    __shared__ float wsum[BLOCK / 64];
    __shared__ float s_spike;
    if ((tid & 63) == 0) wsum[tid >> 6] = partial;
    __syncthreads();

    if (tid == 0) {
        float cur = wsum[0] + wsum[1] + wsum[2] + wsum[3];
        float v   = mp[o] * 0.8f + cur;
        float a   = at[o];
        float sp  = (v >= a) ? 1.0f : 0.0f;
        spikes_out[o] = sp;
        vmem_out[o]   = v * (1.0f - sp) * 0.2f;
        float nt = a + (sp - 0.05f) * 0.1f;
        thr_out[o] = fminf(fmaxf(nt, 0.5f), 10.0f);
        s_spike = sp;
    }
    __syncthreads();

    // ---- Phase 2: trace update  clip(0.7*t + 3*spike*x, 0, 10)
    const float sp3 = s_spike * 3.0f;
    const float4* __restrict__ tr4  = reinterpret_cast<const float4*>(trace + (size_t)o * IN_F);
    float4* __restrict__       out4 = reinterpret_cast<float4*>(trace_out + (size_t)o * IN_F);

    #pragma unroll 4
    for (int i = tid; i < n4; i += BLOCK) {
        float4 t  = tr4[i];
        float4 xv = x4[i];
        float4 r;
        r.x = fminf(fmaxf(t.x * 0.7f + sp3 * xv.x, 0.0f), 10.0f);
        r.y = fminf(fmaxf(t.y * 0.7f + sp3 * xv.y, 0.0f), 10.0f);
        r.z = fminf(fmaxf(t.z * 0.7f + sp3 * xv.z, 0.0f), 10.0f);
        r.w = fminf(fmaxf(t.w * 0.7f + sp3 * xv.w, 0.0f), 10.0f);
        out4[i] = r;
    }
}

extern "C" void kernel_launch(void* const* d_in, const int* in_sizes, int n_in,
                              void* d_out, int out_size, void* d_ws, size_t ws_size,
                              hipStream_t stream) {
    const float* x     = (const float*)d_in[0];  // spike_input [8192]
    const float* syn   = (const float*)d_in[1];  // synapse_states [8192,8192]
    const float* mp    = (const float*)d_in[2];  // membrane_potential [8192]
    const float* at    = (const float*)d_in[3];  // adaptive_threshold [8192]
    const float* trace = (const float*)d_in[4];  // eligibility_trace [8192,8192]

    float* out        = (float*)d_out;
    float* spikes_out = out;                                    // [8192]
    float* vmem_out   = out + OUT_F;                            // [8192]
    float* trace_out  = out + 2 * (size_t)OUT_F;                // [8192*8192]
    float* thr_out    = out + 2 * (size_t)OUT_F + (size_t)OUT_F * IN_F; // [8192]

    snn_fused_kernel<<<OUT_F, BLOCK, 0, stream>>>(
        x, syn, mp, at, trace, spikes_out, vmem_out, trace_out, thr_out);
}